// Round 1
// baseline (5219.106 us; speedup 1.0000x reference)
//
#include <hip/hip_runtime.h>

#define NUSERS 100000
#define NITEMS 50000
#define DIM 64
#define NLAYERS 3

// ---------------- degree accumulation ----------------
__global__ void degree_kernel(const int* __restrict__ tu, const int* __restrict__ ti,
                              float* __restrict__ du, float* __restrict__ di, int E) {
    int stride = gridDim.x * blockDim.x;
    for (int e = blockIdx.x * blockDim.x + threadIdx.x; e < E; e += stride) {
        atomicAdd(&du[tu[e]], 1.0f);
        atomicAdd(&di[ti[e]], 1.0f);
    }
}

// ---------------- per-edge symmetric norm ----------------
__global__ void norm_kernel(const int* __restrict__ tu, const int* __restrict__ ti,
                            const float* __restrict__ du, const float* __restrict__ di,
                            float* __restrict__ nrm, int E) {
    int stride = gridDim.x * blockDim.x;
    for (int e = blockIdx.x * blockDim.x + threadIdx.x; e < E; e += stride) {
        float a = fmaxf(du[tu[e]], 1.0f);
        float b = fmaxf(di[ti[e]], 1.0f);
        nrm[e] = 1.0f / sqrtf(a * b);
    }
}

// ---------------- fused bidirectional scatter ----------------
// 16 threads per edge, 4 dims each (float4). Gathers both endpoint rows,
// scatter-adds weighted messages to both msg buffers.
__global__ void scatter_kernel(const float* __restrict__ u_emb, const float* __restrict__ i_emb,
                               const int* __restrict__ tu, const int* __restrict__ ti,
                               const float* __restrict__ nrm,
                               float* __restrict__ msg_u, float* __restrict__ msg_i, int E) {
    int t = blockIdx.x * blockDim.x + threadIdx.x;
    int e = t >> 4;
    if (e >= E) return;
    int q = (t & 15) << 2;
    int u = tu[e];
    int i = ti[e];
    float n = nrm[e];
    float4 iv = *reinterpret_cast<const float4*>(i_emb + (size_t)i * DIM + q);
    float4 uv = *reinterpret_cast<const float4*>(u_emb + (size_t)u * DIM + q);
    float* mu = msg_u + (size_t)u * DIM + q;
    float* mi = msg_i + (size_t)i * DIM + q;
    atomicAdd(mu + 0, iv.x * n);
    atomicAdd(mu + 1, iv.y * n);
    atomicAdd(mu + 2, iv.z * n);
    atomicAdd(mu + 3, iv.w * n);
    atomicAdd(mi + 0, uv.x * n);
    atomicAdd(mi + 1, uv.y * n);
    atomicAdd(mi + 2, uv.z * n);
    atomicAdd(mi + 3, uv.w * n);
}

// ---------------- beta-gated user residual ----------------
// u_new (already holding msg_u) += tanh(beta_w[u,layer]) * u_old
__global__ void update_u_kernel(const float* __restrict__ u_old, const float* __restrict__ beta_w,
                                float* __restrict__ u_new, int layer, int n4) {
    int t = blockIdx.x * blockDim.x + threadIdx.x;
    if (t >= n4) return;
    int u = t >> 4;
    float b = tanhf(beta_w[u * NLAYERS + layer]);
    float4 m = reinterpret_cast<float4*>(u_new)[t];
    float4 o = reinterpret_cast<const float4*>(u_old)[t];
    m.x += b * o.x;
    m.y += b * o.y;
    m.z += b * o.z;
    m.w += b * o.w;
    reinterpret_cast<float4*>(u_new)[t] = m;
}

extern "C" void kernel_launch(void* const* d_in, const int* in_sizes, int n_in,
                              void* d_out, int out_size, void* d_ws, size_t ws_size,
                              hipStream_t stream) {
    const float* users_w = (const float*)d_in[0];
    const float* items_w = (const float*)d_in[1];
    const float* beta_w  = (const float*)d_in[2];
    const int*   tu      = (const int*)d_in[3];
    const int*   ti      = (const int*)d_in[4];
    const int    E       = in_sizes[3];
    float*       out     = (float*)d_out;

    // ---- workspace layout (all 1 KiB aligned) ----
    char* ws = (char*)d_ws;
    size_t off = 0;
    auto take = [&](size_t nfloats) {
        float* p = (float*)(ws + off);
        off += (nfloats * sizeof(float) + 1023) & ~(size_t)1023;
        return p;
    };
    float* deg = take(NUSERS + NITEMS);          // du | di contiguous
    float* du  = deg;
    float* di  = deg + NUSERS;
    float* nrm = take(E);
    float* bufU = take((size_t)(NUSERS + NITEMS) * DIM); // uB | iB contiguous
    float* bufI = bufU + (size_t)NUSERS * DIM;

    float* outU = out;
    float* outI = out + (size_t)NUSERS * DIM;

    const int blk = 256;

    // degrees + norm (once)
    hipMemsetAsync(deg, 0, (size_t)(NUSERS + NITEMS) * sizeof(float), stream);
    degree_kernel<<<2048, blk, 0, stream>>>(tu, ti, du, di, E);
    norm_kernel<<<2048, blk, 0, stream>>>(tu, ti, du, di, nrm, E);

    // ping-pong: layer0 -> d_out, layer1 -> ws buf, layer2 -> d_out
    float* msgU[NLAYERS] = {outU, bufU, outU};
    float* msgI[NLAYERS] = {outI, bufI, outI};

    const float* ue = users_w;
    const float* ie = items_w;

    int scatter_threads = E * 16;
    int scatter_blocks  = (scatter_threads + blk - 1) / blk;
    int n4 = NUSERS * (DIM / 4);
    int upd_blocks = (n4 + blk - 1) / blk;

    for (int l = 0; l < NLAYERS; ++l) {
        if (msgU[l] == outU) {
            hipMemsetAsync(out, 0, (size_t)out_size * sizeof(float), stream);
        } else {
            hipMemsetAsync(bufU, 0, (size_t)(NUSERS + NITEMS) * DIM * sizeof(float), stream);
        }
        scatter_kernel<<<scatter_blocks, blk, 0, stream>>>(ue, ie, tu, ti, nrm,
                                                           msgU[l], msgI[l], E);
        update_u_kernel<<<upd_blocks, blk, 0, stream>>>(ue, beta_w, msgU[l], l, n4);
        ue = msgU[l];
        ie = msgI[l];
    }
}

// Round 2
// 790.326 us; speedup vs baseline: 6.6037x; 6.6037x over previous
//
#include <hip/hip_runtime.h>

#define NUSERS 100000
#define NITEMS 50000
#define NV (NUSERS + NITEMS)
#define DIM 64
#define NLAYERS 3

// ---------------- combined degree histogram ----------------
__global__ void degree_kernel(const int* __restrict__ tu, const int* __restrict__ ti,
                              int* __restrict__ deg, int E) {
    int stride = gridDim.x * blockDim.x;
    for (int e = blockIdx.x * blockDim.x + threadIdx.x; e < E; e += stride) {
        atomicAdd(&deg[tu[e]], 1);
        atomicAdd(&deg[NUSERS + ti[e]], 1);
    }
}

// ---------------- single-block exclusive scan over N elements ----------------
__global__ void scan_kernel(const int* __restrict__ deg, int* __restrict__ off, int N) {
    __shared__ int lsum[1024];
    int t = threadIdx.x;
    int chunk = (N + 1023) >> 10;
    int s = t * chunk;
    int e = min(s + chunk, N);
    int sum = 0;
    for (int i = s; i < e; ++i) sum += deg[i];
    lsum[t] = sum;
    __syncthreads();
    // Hillis-Steele inclusive scan
    for (int d = 1; d < 1024; d <<= 1) {
        int v = (t >= d) ? lsum[t - d] : 0;
        __syncthreads();
        lsum[t] += v;
        __syncthreads();
    }
    int run = lsum[t] - sum;  // exclusive prefix of this thread's chunk
    for (int i = s; i < e; ++i) { off[i] = run; run += deg[i]; }
    if (t == 1023) off[N] = lsum[1023];
}

// ---------------- cursors + reciprocal-sqrt-degree ----------------
__global__ void prep_kernel(const int* __restrict__ deg, const int* __restrict__ off,
                            int* __restrict__ cur, float* __restrict__ rsd, int N) {
    int i = blockIdx.x * blockDim.x + threadIdx.x;
    if (i >= N) return;
    cur[i] = off[i];
    rsd[i] = rsqrtf(fmaxf((float)deg[i], 1.0f));
}

// ---------------- CSR bucket fill (both directions into one array) ----------------
__global__ void fill_kernel(const int* __restrict__ tu, const int* __restrict__ ti,
                            int* __restrict__ cur, int* __restrict__ adj, int E) {
    int stride = gridDim.x * blockDim.x;
    for (int e = blockIdx.x * blockDim.x + threadIdx.x; e < E; e += stride) {
        int u = tu[e];
        int it = ti[e];
        int pu = atomicAdd(&cur[u], 1);
        adj[pu] = it;                       // user's neighbor list holds item ids
        int pi = atomicAdd(&cur[NUSERS + it], 1);
        adj[pi] = u;                        // item's neighbor list holds user ids
    }
}

// ---------------- gather-reduce propagation (one wave per vertex) ----------------
__global__ void gather_kernel(const float* __restrict__ src_u, const float* __restrict__ src_i,
                              const float* __restrict__ rsd, const int* __restrict__ off,
                              const int* __restrict__ adj, const float* __restrict__ beta_w,
                              float* __restrict__ dst, int layer) {
    int wid = (blockIdx.x * blockDim.x + threadIdx.x) >> 6;
    int lane = threadIdx.x & 63;
    if (wid >= NV) return;
    int s = off[wid];
    int e = off[wid + 1];
    bool isU = wid < NUSERS;
    const float* src = isU ? src_i : src_u;          // neighbors live on the other side
    const float* rw  = isU ? rsd + NUSERS : rsd;     // neighbor degree norms
    float a0 = 0.f, a1 = 0.f, a2 = 0.f, a3 = 0.f;
    int k = s;
    for (; k + 4 <= e; k += 4) {
        int i0 = adj[k];
        int i1 = adj[k + 1];
        int i2 = adj[k + 2];
        int i3 = adj[k + 3];
        a0 += rw[i0] * src[(size_t)i0 * DIM + lane];
        a1 += rw[i1] * src[(size_t)i1 * DIM + lane];
        a2 += rw[i2] * src[(size_t)i2 * DIM + lane];
        a3 += rw[i3] * src[(size_t)i3 * DIM + lane];
    }
    for (; k < e; ++k) {
        int i0 = adj[k];
        a0 += rw[i0] * src[(size_t)i0 * DIM + lane];
    }
    float res = ((a0 + a1) + (a2 + a3)) * rsd[wid];
    if (isU) {
        float b = tanhf(beta_w[wid * NLAYERS + layer]);
        res += b * src_u[(size_t)wid * DIM + lane];  // beta-gated residual
    }
    dst[(size_t)wid * DIM + lane] = res;
}

extern "C" void kernel_launch(void* const* d_in, const int* in_sizes, int n_in,
                              void* d_out, int out_size, void* d_ws, size_t ws_size,
                              hipStream_t stream) {
    const float* users_w = (const float*)d_in[0];
    const float* items_w = (const float*)d_in[1];
    const float* beta_w  = (const float*)d_in[2];
    const int*   tu      = (const int*)d_in[3];
    const int*   ti      = (const int*)d_in[4];
    const int    E       = in_sizes[3];
    float*       out     = (float*)d_out;

    // ---- workspace layout ----
    char* ws = (char*)d_ws;
    size_t woff = 0;
    auto take = [&](size_t bytes) {
        char* p = ws + woff;
        woff += (bytes + 1023) & ~(size_t)1023;
        return p;
    };
    int*   deg = (int*)take((size_t)NV * sizeof(int));
    int*   off = (int*)take((size_t)(NV + 1) * sizeof(int));
    int*   cur = (int*)take((size_t)NV * sizeof(int));
    float* rsd = (float*)take((size_t)NV * sizeof(float));
    int*   adj = (int*)take((size_t)2 * E * sizeof(int));
    float* buf = (float*)take((size_t)NV * DIM * sizeof(float));

    const int blk = 256;

    // ---- CSR construction (per call; deterministic degrees, bucket order free) ----
    hipMemsetAsync(deg, 0, (size_t)NV * sizeof(int), stream);
    degree_kernel<<<2048, blk, 0, stream>>>(tu, ti, deg, E);
    scan_kernel<<<1, 1024, 0, stream>>>(deg, off, NV);
    prep_kernel<<<(NV + blk - 1) / blk, blk, 0, stream>>>(deg, off, cur, rsd, NV);
    fill_kernel<<<2048, blk, 0, stream>>>(tu, ti, cur, adj, E);

    // ---- 3 propagation layers: (in) -> d_out -> ws buf -> d_out ----
    int gblocks = ((size_t)NV * 64 + blk - 1) / blk;

    // layer 0: sources are the raw weights
    gather_kernel<<<gblocks, blk, 0, stream>>>(users_w, items_w, rsd, off, adj, beta_w,
                                               out, 0);
    // layer 1: source = d_out, dest = ws buffer
    gather_kernel<<<gblocks, blk, 0, stream>>>(out, out + (size_t)NUSERS * DIM, rsd, off,
                                               adj, beta_w, buf, 1);
    // layer 2: source = ws buffer, dest = d_out
    gather_kernel<<<gblocks, blk, 0, stream>>>(buf, buf + (size_t)NUSERS * DIM, rsd, off,
                                               adj, beta_w, out, 2);
}

// Round 3
// 519.519 us; speedup vs baseline: 10.0460x; 1.5213x over previous
//
#include <hip/hip_runtime.h>

#define NUSERS 100000
#define NITEMS 50000
#define NV (NUSERS + NITEMS)
#define DIM 64
#define NLAYERS 3
#define SCHUNK 1024                   // elements per scan block
#define NSB ((NV + SCHUNK - 1) / SCHUNK)

// ---------------- combined degree histogram ----------------
__global__ void degree_kernel(const int* __restrict__ tu, const int* __restrict__ ti,
                              int* __restrict__ deg, int E) {
    int stride = gridDim.x * blockDim.x;
    for (int e = blockIdx.x * blockDim.x + threadIdx.x; e < E; e += stride) {
        atomicAdd(&deg[tu[e]], 1);
        atomicAdd(&deg[NUSERS + ti[e]], 1);
    }
}

// ---------------- scan stage 1: per-block partial sums ----------------
__global__ void partial_kernel(const int* __restrict__ deg, int* __restrict__ bsum, int N) {
    __shared__ int sh[256];
    int b = blockIdx.x, t = threadIdx.x;
    int base = b * SCHUNK;
    int sum = 0;
    for (int j = t; j < SCHUNK; j += 256) {
        int i = base + j;
        if (i < N) sum += deg[i];
    }
    sh[t] = sum;
    __syncthreads();
    for (int d = 128; d > 0; d >>= 1) {
        if (t < d) sh[t] += sh[t + d];
        __syncthreads();
    }
    if (t == 0) bsum[b] = sh[0];
}

// ---------------- scan stage 2: exclusive scan of partials (1 block) ----------------
__global__ void scanp_kernel(int* __restrict__ bsum, int NB) {
    __shared__ int sh[256];
    int t = threadIdx.x;
    int v = (t < NB) ? bsum[t] : 0;
    sh[t] = v;
    __syncthreads();
    for (int d = 1; d < 256; d <<= 1) {
        int x = (t >= d) ? sh[t - d] : 0;
        __syncthreads();
        sh[t] += x;
        __syncthreads();
    }
    if (t < NB) bsum[t] = sh[t] - v;   // exclusive
}

// ---------------- scan stage 3: final offsets + cursors + rsd (fused prep) ----------------
__global__ void finalscan_kernel(const int* __restrict__ deg, const int* __restrict__ bsum,
                                 int* __restrict__ off, int* __restrict__ cur,
                                 float* __restrict__ rsd, int N, int total) {
    __shared__ int sh[256];
    int b = blockIdx.x, t = threadIdx.x;
    int i0 = b * SCHUNK + t * 4;
    int v0 = 0, v1 = 0, v2 = 0, v3 = 0;
    if (i0 + 0 < N) v0 = deg[i0 + 0];
    if (i0 + 1 < N) v1 = deg[i0 + 1];
    if (i0 + 2 < N) v2 = deg[i0 + 2];
    if (i0 + 3 < N) v3 = deg[i0 + 3];
    int s = v0 + v1 + v2 + v3;
    sh[t] = s;
    __syncthreads();
    for (int d = 1; d < 256; d <<= 1) {
        int x = (t >= d) ? sh[t - d] : 0;
        __syncthreads();
        sh[t] += x;
        __syncthreads();
    }
    int o = sh[t] - s + bsum[b];
    int ov[4] = {o, o + v0, o + v0 + v1, o + v0 + v1 + v2};
    int dv[4] = {v0, v1, v2, v3};
#pragma unroll
    for (int j = 0; j < 4; ++j) {
        int i = i0 + j;
        if (i < N) {
            off[i] = ov[j];
            cur[i] = ov[j];
            rsd[i] = rsqrtf(fmaxf((float)dv[j], 1.0f));
        }
    }
    if (b == 0 && t == 0) off[N] = total;
}

// ---------------- CSR fill with precomputed edge weights ----------------
// each adjacency slot stores (neighbor_id, rsd[u]*rsd[i]) so the gather loop
// needs no norm lookups at all.
__global__ void fill_kernel(const int* __restrict__ tu, const int* __restrict__ ti,
                            const float* __restrict__ rsd, int* __restrict__ cur,
                            int2* __restrict__ adjw, int E) {
    int stride = gridDim.x * blockDim.x;
    for (int e = blockIdx.x * blockDim.x + threadIdx.x; e < E; e += stride) {
        int u = tu[e];
        int it = ti[e];
        float w = rsd[u] * rsd[NUSERS + it];
        int wi = __float_as_int(w);
        int pu = atomicAdd(&cur[u], 1);
        adjw[pu] = make_int2(it, wi);            // user's list: item ids
        int pi = atomicAdd(&cur[NUSERS + it], 1);
        adjw[pi] = make_int2(u, wi);             // item's list: user ids
    }
}

// ---------------- gather-reduce propagation (one wave per vertex) ----------------
__global__ void gather_kernel(const float* __restrict__ src_u, const float* __restrict__ src_i,
                              const int* __restrict__ off, const int2* __restrict__ adjw,
                              const float* __restrict__ beta_w,
                              float* __restrict__ dst, int layer) {
    int wid = (blockIdx.x * blockDim.x + threadIdx.x) >> 6;
    int lane = threadIdx.x & 63;
    if (wid >= NV) return;
    int s = off[wid];
    int e = off[wid + 1];
    bool isU = wid < NUSERS;
    const float* src = isU ? src_i : src_u;      // neighbors live on the other side
    float a0 = 0.f, a1 = 0.f, a2 = 0.f, a3 = 0.f;
    int k = s;
    for (; k + 4 <= e; k += 4) {
        int2 p0 = adjw[k];
        int2 p1 = adjw[k + 1];
        int2 p2 = adjw[k + 2];
        int2 p3 = adjw[k + 3];
        a0 += __int_as_float(p0.y) * src[(size_t)p0.x * DIM + lane];
        a1 += __int_as_float(p1.y) * src[(size_t)p1.x * DIM + lane];
        a2 += __int_as_float(p2.y) * src[(size_t)p2.x * DIM + lane];
        a3 += __int_as_float(p3.y) * src[(size_t)p3.x * DIM + lane];
    }
    for (; k < e; ++k) {
        int2 p0 = adjw[k];
        a0 += __int_as_float(p0.y) * src[(size_t)p0.x * DIM + lane];
    }
    float res = (a0 + a1) + (a2 + a3);
    if (isU) {
        float b = tanhf(beta_w[wid * NLAYERS + layer]);
        res += b * src_u[(size_t)wid * DIM + lane];  // beta-gated residual
    }
    dst[(size_t)wid * DIM + lane] = res;
}

extern "C" void kernel_launch(void* const* d_in, const int* in_sizes, int n_in,
                              void* d_out, int out_size, void* d_ws, size_t ws_size,
                              hipStream_t stream) {
    const float* users_w = (const float*)d_in[0];
    const float* items_w = (const float*)d_in[1];
    const float* beta_w  = (const float*)d_in[2];
    const int*   tu      = (const int*)d_in[3];
    const int*   ti      = (const int*)d_in[4];
    const int    E       = in_sizes[3];
    float*       out     = (float*)d_out;

    // ---- workspace layout ----
    char* ws = (char*)d_ws;
    size_t woff = 0;
    auto take = [&](size_t bytes) {
        char* p = ws + woff;
        woff += (bytes + 1023) & ~(size_t)1023;
        return p;
    };
    int*   deg  = (int*)take((size_t)NV * sizeof(int));
    int*   off  = (int*)take((size_t)(NV + 1) * sizeof(int));
    int*   cur  = (int*)take((size_t)NV * sizeof(int));
    float* rsd  = (float*)take((size_t)NV * sizeof(float));
    int*   bsum = (int*)take((size_t)NSB * sizeof(int));
    int2*  adjw = (int2*)take((size_t)2 * E * sizeof(int2));
    float* buf  = (float*)take((size_t)NV * DIM * sizeof(float));

    const int blk = 256;

    // ---- CSR construction ----
    hipMemsetAsync(deg, 0, (size_t)NV * sizeof(int), stream);
    degree_kernel<<<2048, blk, 0, stream>>>(tu, ti, deg, E);
    partial_kernel<<<NSB, 256, 0, stream>>>(deg, bsum, NV);
    scanp_kernel<<<1, 256, 0, stream>>>(bsum, NSB);
    finalscan_kernel<<<NSB, 256, 0, stream>>>(deg, bsum, off, cur, rsd, NV, 2 * E);
    fill_kernel<<<2048, blk, 0, stream>>>(tu, ti, rsd, cur, adjw, E);

    // ---- 3 propagation layers: (in) -> d_out -> ws buf -> d_out ----
    int gblocks = ((size_t)NV * 64 + blk - 1) / blk;

    gather_kernel<<<gblocks, blk, 0, stream>>>(users_w, items_w, off, adjw, beta_w,
                                               out, 0);
    gather_kernel<<<gblocks, blk, 0, stream>>>(out, out + (size_t)NUSERS * DIM, off,
                                               adjw, beta_w, buf, 1);
    gather_kernel<<<gblocks, blk, 0, stream>>>(buf, buf + (size_t)NUSERS * DIM, off,
                                               adjw, beta_w, out, 2);
}